// Round 2
// baseline (201.605 us; speedup 1.0000x reference)
//
#include <hip/hip_runtime.h>
#include <hip/hip_bf16.h>
#include <cstdint>
#include <cstddef>

// Problem constants (fixed by the reference)
#define NCAT   8
#define DIN    64
#define HID    1024
#define NBATCH 256
#define HSEQ   64
#define NTOK   (NBATCH * HSEQ)   // 16384
#define MAXTILES 132             // sum ceil(nb_c/2) <= 128 + 4

typedef __bf16 bf16x8 __attribute__((ext_vector_type(8)));
typedef __bf16 bf16x4 __attribute__((ext_vector_type(4)));
typedef float  f32x4  __attribute__((ext_vector_type(4)));

__device__ __forceinline__ void async16(const void* g, void* l) {
    __builtin_amdgcn_global_load_lds(
        (const __attribute__((address_space(1))) unsigned int*)g,
        (__attribute__((address_space(3))) unsigned int*)l,
        16, 0, 0);
}

// ---------------- setup: counting-sort batches by category, build tile table ----------------
// meta layout (ints): order[256] @0, tileB0[160] @256, tileB1[160] @416,
//                     tileCat[160] @576, ntiles @736
__global__ void setup_kernel(const int* __restrict__ cat, int* __restrict__ meta) {
    __shared__ int scat[NBATCH];
    __shared__ int cnt[NCAT], pfx[NCAT + 1];
    const int tid = threadIdx.x;
    const int c = cat[tid];
    scat[tid] = c;
    if (tid < NCAT) cnt[tid] = 0;
    __syncthreads();
    atomicAdd(&cnt[c], 1);
    __syncthreads();
    if (tid == 0) {
        pfx[0] = 0;
        for (int i = 0; i < NCAT; ++i) pfx[i + 1] = pfx[i] + cnt[i];
    }
    __syncthreads();
    int r = 0;
    for (int b = 0; b < tid; ++b) r += (scat[b] == c);
    meta[pfx[c] + r] = tid;                 // order[]
    __threadfence_block();
    __syncthreads();
    if (tid == 0) {
        int nt = 0;
        for (int cc = 0; cc < NCAT; ++cc) {
            const int base = pfx[cc], n = cnt[cc];
            for (int j = 0; j < n; j += 2) {
                meta[256 + nt] = meta[base + j];                      // tileB0
                meta[416 + nt] = (j + 1 < n) ? meta[base + j + 1] : -1; // tileB1
                meta[576 + nt] = cc;                                  // tileCat
                ++nt;
            }
        }
        meta[736] = nt;
    }
}

// ---------------- prep kernels ----------------

__global__ void pe_kernel(float* __restrict__ pe) {
    const int t = blockIdx.x;        // 0..63
    const int i = threadIdx.x;       // 0..511
    const float div = expf((float)(2 * i) * (-9.210340371976184f / 1024.f));
    const float a = (float)t * div;
    pe[t * HID + 2 * i]     = sinf(a);
    pe[t * HID + 2 * i + 1] = cosf(a);
}

__global__ void cvt_x_kernel(const float* __restrict__ x, __bf16* __restrict__ xb) {
    const size_t i = (size_t)blockIdx.x * blockDim.x + threadIdx.x;
    const float4 v = ((const float4*)x)[i];
    bf16x4 o = { (__bf16)v.x, (__bf16)v.y, (__bf16)v.z, (__bf16)v.w };
    *(bf16x4*)(xb + 4 * i) = o;
}

// W [C][K][N] f32 -> Wt [C][N][K] bf16 (64x64 LDS-tiled transpose)
__global__ __launch_bounds__(256)
void transpose_kernel(const float* __restrict__ W, __bf16* __restrict__ Wt,
                      const int K, const int N) {
    __shared__ float tile[64][65];
    const int c = blockIdx.z;
    const float* Wc = W + (size_t)c * K * N;
    __bf16* Wtc = Wt + (size_t)c * N * K;
    const int k0 = blockIdx.y * 64, n0 = blockIdx.x * 64;
    const int t = threadIdx.x;
    const int cl = (t & 15) * 4, rw = t >> 4;
#pragma unroll
    for (int p = 0; p < 4; ++p) {
        const int r = rw + p * 16;
        const float4 v = *(const float4*)(Wc + (size_t)(k0 + r) * N + (n0 + cl));
        tile[r][cl]     = v.x;
        tile[r][cl + 1] = v.y;
        tile[r][cl + 2] = v.z;
        tile[r][cl + 3] = v.w;
    }
    __syncthreads();
    const int n = t >> 2, ks = (t & 3) * 16;
    bf16x8 o0, o1;
#pragma unroll
    for (int i = 0; i < 8; ++i) o0[i] = (__bf16)tile[ks + i][n];
#pragma unroll
    for (int i = 0; i < 8; ++i) o1[i] = (__bf16)tile[ks + 8 + i][n];
    __bf16* dst = Wtc + (size_t)(n0 + n) * K + (k0 + ks);
    *(bf16x8*)dst = o0;
    *(bf16x8*)(dst + 8) = o1;
}

// ---------------- category-grouped 128x128 GEMM (m97 structure) ----------------
// A: [NTOK][K] bf16 row-major (token = batch*64 + t). Bt: [C][HID][K] bf16.
// Tile table groups 2 same-category batches -> 128 grouped rows per m-tile.
// 4 waves in 2x2 grid, each owns 64x64 (4x4 of 16x16x32 MFMA). Single-buffered
// 32 KB LDS, 2-barrier K-loop, global_load_lds width-16 staging.
// EPI: 0 = +bias, relu, +pe -> bf16 ; 1 = +bias, relu -> bf16 ; 2 = +bias -> f32
template <int K, int EPI>
__global__ __launch_bounds__(256, 4)
void gemm_cat(const __bf16* __restrict__ A,
              const __bf16* __restrict__ Bt,
              const float* __restrict__ bias,
              const float* __restrict__ pe,
              const int* __restrict__ meta,
              __bf16* __restrict__ hout,
              float* __restrict__ fout) {
    __shared__ __bf16 Ab[128 * 64];    // 16 KB
    __shared__ __bf16 Bb[128 * 64];    // 16 KB
    const int tid = threadIdx.x;
    const int lane = tid & 63;
    const int wv = tid >> 6;           // 0..3
    const int wm = wv >> 1, wn = wv & 1;
    const int mt = blockIdx.y;
    if (mt >= meta[736]) return;
    const int b0  = meta[256 + mt];
    const int b1  = meta[416 + mt];
    const int cid = meta[576 + mt];
    const int bb  = (b1 < 0) ? b0 : b1;
    const int n0 = blockIdx.x * 128;

    const char* Ag0 = (const char*)(A + (size_t)b0 * HSEQ * K);
    const char* Ag1 = (const char*)(A + (size_t)bb * HSEQ * K);
    const char* Bg  = (const char*)(Bt + ((size_t)cid * HID + n0) * K);

    // staging geometry: tile = 128 rows x 128 B; 256 threads x 16 B x 4 issues
    const int srow = tid >> 3;          // 0..31 (row within 32-row issue group)
    const int scol = (tid & 7) * 16;    // byte within 128 B row

    auto stage = [&](int k0) {
        const size_t kb = (size_t)k0 * 2;
#pragma unroll
        for (int j = 0; j < 4; ++j) {   // A tile rows j*32 + srow
            const int row = j * 32 + srow;
            const char* src = (j < 2 ? Ag0 + (size_t)row * (K * 2)
                                     : Ag1 + (size_t)(row - 64) * (K * 2)) + kb + scol;
            async16(src, (char*)Ab + j * 4096 + tid * 16);
        }
#pragma unroll
        for (int j = 0; j < 4; ++j) {   // B tile rows j*32 + srow
            const int row = j * 32 + srow;
            const char* src = Bg + (size_t)row * (K * 2) + kb + scol;
            async16(src, (char*)Bb + j * 4096 + tid * 16);
        }
    };

    f32x4 acc[4][4] = {};
    const int lr = lane & 15, lh = lane >> 4;

    const int NT = K / 64;
    for (int t = 0; t < NT; ++t) {
        stage(t * 64);
        __syncthreads();               // vmcnt(0) drain: tile staged
#pragma unroll
        for (int kk = 0; kk < 2; ++kk) {
            bf16x8 af[4], bfr[4];
#pragma unroll
            for (int mi = 0; mi < 4; ++mi)
                af[mi] = *(const bf16x8*)&Ab[(wm * 64 + mi * 16 + lr) * 64 + kk * 32 + lh * 8];
#pragma unroll
            for (int ni = 0; ni < 4; ++ni)
                bfr[ni] = *(const bf16x8*)&Bb[(wn * 64 + ni * 16 + lr) * 64 + kk * 32 + lh * 8];
#pragma unroll
            for (int mi = 0; mi < 4; ++mi)
#pragma unroll
                for (int ni = 0; ni < 4; ++ni)
                    acc[mi][ni] = __builtin_amdgcn_mfma_f32_16x16x32_bf16(
                        af[mi], bfr[ni], acc[mi][ni], 0, 0, 0);
        }
        __syncthreads();               // all reads done before restage
    }

    // epilogue: C/D layout col = lane&15, row = (lane>>4)*4 + r
    const bool doStore = (wm == 0) || (b1 >= 0);
    if (!doStore) return;
    const int batch = wm ? b1 : b0;
    const int colg = lane & 15;
    const int row4 = (lane >> 4) * 4;
#pragma unroll
    for (int ni = 0; ni < 4; ++ni) {
        const int n = n0 + wn * 64 + ni * 16 + colg;
        const float bv = bias[cid * HID + n];
#pragma unroll
        for (int mi = 0; mi < 4; ++mi) {
#pragma unroll
            for (int r = 0; r < 4; ++r) {
                const int tok = mi * 16 + row4 + r;   // token within batch = PE index
                const size_t gi = ((size_t)batch * HSEQ + tok) * HID + n;
                float v = acc[mi][ni][r] + bv;
                if constexpr (EPI == 0) {
                    v = fmaxf(v, 0.f) + pe[tok * HID + n];
                    hout[gi] = (__bf16)v;
                } else if constexpr (EPI == 1) {
                    v = fmaxf(v, 0.f);
                    hout[gi] = (__bf16)v;
                } else {
                    fout[gi] = v;
                }
            }
        }
    }
}

// ---------------- launcher ----------------

extern "C" void kernel_launch(void* const* d_in, const int* in_sizes, int n_in,
                              void* d_out, int out_size, void* d_ws, size_t ws_size,
                              hipStream_t stream) {
    (void)in_sizes; (void)n_in; (void)out_size; (void)ws_size;
    const float* x   = (const float*)d_in[0];
    const int*   cat = (const int*)d_in[1];
    const float* W1  = (const float*)d_in[2];
    const float* b1  = (const float*)d_in[3];
    const float* W2  = (const float*)d_in[4];
    const float* b2  = (const float*)d_in[5];
    const float* W3  = (const float*)d_in[6];
    const float* b3  = (const float*)d_in[7];
    float* out = (float*)d_out;

    // Workspace layout (67.1 MB; xb/W1t/pe are dead after L1 and time-alias h2):
    char* ws = (char*)d_ws;
    int*    meta = (int*)ws;                             // [0, 8192)
    __bf16* xb   = (__bf16*)(ws + 8192);                 // 2 MB   (L1 only)
    __bf16* W1t  = (__bf16*)(ws + 8192 + 2097152);       // 1 MB   (L1 only)
    float*  pe   = (float*) (ws + 8192 + 3145728);       // 256 KB (L1 only)
    __bf16* h2   = (__bf16*)(ws + 8192);                 // 32 MB  (written in L2; aliases the above)
    __bf16* W2t  = (__bf16*)(ws + 33562624);             // 16 MB
    __bf16* W3t  = (__bf16*)(ws + 50339840);             // 16 MB
    // h1 (bf16, 32 MB) lives in the first half of d_out (f32 64 MB);
    // fully consumed by L2 before L3 overwrites d_out.
    __bf16* h1 = (__bf16*)d_out;

    setup_kernel<<<dim3(1), dim3(NBATCH), 0, stream>>>(cat, meta);
    pe_kernel<<<dim3(HSEQ), dim3(512), 0, stream>>>(pe);
    cvt_x_kernel<<<dim3(NTOK * DIN / 4 / 256), dim3(256), 0, stream>>>(x, xb);
    transpose_kernel<<<dim3(16, 1, NCAT),  dim3(256), 0, stream>>>(W1, W1t, DIN, HID);
    transpose_kernel<<<dim3(16, 16, NCAT), dim3(256), 0, stream>>>(W2, W2t, HID, HID);
    transpose_kernel<<<dim3(16, 16, NCAT), dim3(256), 0, stream>>>(W3, W3t, HID, HID);

    gemm_cat<DIN, 0><<<dim3(8, MAXTILES), dim3(256), 0, stream>>>(xb, W1t, b1, pe, meta, h1, nullptr);
    gemm_cat<HID, 1><<<dim3(8, MAXTILES), dim3(256), 0, stream>>>(h1, W2t, b2, nullptr, meta, h2, nullptr);
    gemm_cat<HID, 2><<<dim3(8, MAXTILES), dim3(256), 0, stream>>>(h2, W3t, b3, nullptr, meta, nullptr, out);
}